// Round 6
// baseline (468.246 us; speedup 1.0000x reference)
//
#include <hip/hip_runtime.h>
#include <cstdint>
#include <cstddef>

// Problem dims (fixed): B=1, S=4096, D_MODEL=1024, H=16, Dk=64.
#define S_LEN 4096
#define DMODEL 1024
#define NHEADS 16
#define DK 64
#define ACT (S_LEN * DMODEL)     // 4,194,304 elements
#define WELE (DMODEL * DMODEL)   // 1,048,576 elements

typedef __bf16 bf16;
typedef bf16  bf16x2 __attribute__((ext_vector_type(2)));
typedef bf16  bf16x4 __attribute__((ext_vector_type(4)));
typedef bf16  bf16x8 __attribute__((ext_vector_type(8)));
typedef float f32x4  __attribute__((ext_vector_type(4)));
typedef float f32x16 __attribute__((ext_vector_type(16)));
typedef unsigned int uint32x4v __attribute__((ext_vector_type(4)));

// ---- async global->LDS, 16B per lane, offset 0 only. LDS dest = wave-uniform
// base + lane*16. (Round-3-proven form.)
__device__ __forceinline__ void async16(const void* g, void* l) {
    __builtin_amdgcn_global_load_lds(
        (__attribute__((address_space(1))) void*)(uintptr_t)g,
        (__attribute__((address_space(3))) void*)(uintptr_t)l,
        16, 0, 0);
}

__device__ __forceinline__ float fast_exp2(float x) {
#if __has_builtin(__builtin_amdgcn_exp2f)
    return __builtin_amdgcn_exp2f(x);
#else
    return exp2f(x);
#endif
}

// pack two f32 -> one dword of 2 bf16 (compiler emits cvt + pack; m240: do
// NOT hand-write v_cvt_pk_bf16_f32)
__device__ __forceinline__ unsigned pk2(float a, float b) {
    bf16x2 t; t[0] = (bf16)a; t[1] = (bf16)b;
    return __builtin_bit_cast(unsigned, t);
}

// v_permlane32_swap_b32: swaps a's upper 32 lanes with b's lower 32 lanes.
__device__ __forceinline__ void pl32swap(unsigned &a, unsigned &b) {
    asm volatile("v_permlane32_swap_b32 %0, %1" : "+v"(a), "+v"(b));
}

__device__ __forceinline__ bf16x8 mkfrag(unsigned w0, unsigned w1, unsigned w2, unsigned w3) {
    uint32x4v u = { w0, w1, w2, w3 };
    return __builtin_bit_cast(bf16x8, u);
}

// ---------------------------------------------------------------------------
// fp32 -> bf16 converter, 7 tensors in one launch (y = 0..6).
// ---------------------------------------------------------------------------
__global__ void __launch_bounds__(256) cvt7(
    const float* a0, const float* a1, const float* a2,
    const float* w0, const float* w1, const float* w2, const float* w3,
    bf16* oa0, bf16* oa1, bf16* oa2,
    bf16* ow0, bf16* ow1, bf16* ow2, bf16* ow3,
    int nA, int nB)
{
    const float* s; bf16* d; int n4;
    switch (blockIdx.y) {
        case 0: s = a0; d = oa0; n4 = nA; break;
        case 1: s = a1; d = oa1; n4 = nA; break;
        case 2: s = a2; d = oa2; n4 = nA; break;
        case 3: s = w0; d = ow0; n4 = nB; break;
        case 4: s = w1; d = ow1; n4 = nB; break;
        case 5: s = w2; d = ow2; n4 = nB; break;
        default: s = w3; d = ow3; n4 = nB; break;
    }
    int i = blockIdx.x * 256 + threadIdx.x;
    if (i < n4) {
        float4 v = ((const float4*)s)[i];
        bf16x4 r = { (bf16)v.x, (bf16)v.y, (bf16)v.z, (bf16)v.w };
        ((bf16x4*)d)[i] = r;
    }
}

// ---------------------------------------------------------------------------
// MFMA sub-tile compute on a [128][32] LDS tile pair (r8-proven layout).
// ---------------------------------------------------------------------------
__device__ __forceinline__ void gemm_compute_128(
    const bf16* As, const bf16* Bs, f32x4 (&acc)[4][4],
    int wm, int wn, int l16, int quad)
{
    bf16x8 af[4], bfr[4];
#pragma unroll
    for (int i = 0; i < 4; ++i)
        af[i] = *(const bf16x8*)&As[(wm + i * 16 + l16) * 32 + quad * 8];
#pragma unroll
    for (int i = 0; i < 4; ++i)
        bfr[i] = *(const bf16x8*)&Bs[(wn + i * 16 + l16) * 32 + quad * 8];
#pragma unroll
    for (int mi = 0; mi < 4; ++mi)
#pragma unroll
        for (int ni = 0; ni < 4; ++ni)
            acc[mi][ni] = __builtin_amdgcn_mfma_f32_16x16x32_bf16(
                af[mi], bfr[ni], acc[mi][ni], 0, 0, 0);
}

// NT GEMM core, BK=64 as two proven BK=32 sub-tiles per barrier pair.
__device__ __forceinline__ void gemm_core_bk64(
    const bf16* __restrict__ A, const bf16* __restrict__ B,
    bf16* As, bf16* Bs, f32x4 (&acc)[4][4],
    int m0, int n0, int wm, int wn, int K)
{
    const int tid  = threadIdx.x;
    const int wave = tid >> 6;
    const int lane = tid & 63;
    const int quad = lane >> 4;
    const int l16  = lane & 15;

    const int srow = tid >> 2;
    const int scol = (tid & 3) * 8;
    const bf16* Ag = A + (size_t)(m0 + srow) * K + scol;
    const bf16* Bg = B + (size_t)(n0 + srow) * K + scol;
    char* lA = (char*)As + wave * 1024;
    char* lB = (char*)Bs + wave * 1024;

    for (int k0 = 0; k0 < K; k0 += 64) {
        async16(Ag,                       lA);
        async16(Ag + (size_t)64 * K,      lA + 4096);
        async16(Ag + 32,                  lA + 8192);
        async16(Ag + 32 + (size_t)64 * K, lA + 12288);
        async16(Bg,                       lB);
        async16(Bg + (size_t)64 * K,      lB + 4096);
        async16(Bg + 32,                  lB + 8192);
        async16(Bg + 32 + (size_t)64 * K, lB + 12288);
        Ag += 64; Bg += 64;
        __syncthreads();

        gemm_compute_128(As,        Bs,        acc, wm, wn, l16, quad);
        gemm_compute_128(As + 4096, Bs + 4096, acc, wm, wn, l16, quad);
        __syncthreads();
    }
}

// Fused QKV projection (r8 epilogues). blockIdx.z selects {Q,K,V}.
// Q/K: head-major bf16 [h][s][dk], 16B-chunk XOR-swizzled by (s&7) per row.
// V:   transposed TILED bf16 [h][T=t/64][dk][64], chunk-swizzled by (dk&7).
// Q pre-scaled by 0.125*log2e.
__global__ void __launch_bounds__(256) proj_qkv(
    const bf16* __restrict__ Xq, const bf16* __restrict__ Wq, const float* __restrict__ bq, bf16* __restrict__ Qo,
    const bf16* __restrict__ Xk, const bf16* __restrict__ Wk, const float* __restrict__ bk, bf16* __restrict__ Ko,
    const bf16* __restrict__ Xv, const bf16* __restrict__ Wv, const float* __restrict__ bv, bf16* __restrict__ Vo,
    float qscale)
{
    __shared__ __align__(16) bf16 As[2 * 128 * 32];   // 16 KB
    __shared__ __align__(16) bf16 Bs[2 * 128 * 32];   // 16 KB

    const int which = blockIdx.z;
    const bf16*  A    = (which == 0) ? Xq : (which == 1) ? Xk : Xv;
    const bf16*  Bw   = (which == 0) ? Wq : (which == 1) ? Wk : Wv;
    const float* bias = (which == 0) ? bq : (which == 1) ? bk : bv;
    const float  scale = (which == 0) ? qscale : 1.0f;

    const int tid  = threadIdx.x;
    const int wave = tid >> 6;
    const int lane = tid & 63;
    const int quad = lane >> 4;
    const int l16  = lane & 15;
    const int m0 = blockIdx.x * 128;
    const int n0 = blockIdx.y * 128;
    const int wm = (wave & 1) * 64;
    const int wn = (wave >> 1) * 64;

    f32x4 acc[4][4] = {};
    gemm_core_bk64(A, Bw, As, Bs, acc, m0, n0, wm, wn, DMODEL);

    // C/D layout: col(n) = lane&15, row(m) = quad*4 + reg
    if (which < 2) {
        bf16* out = (which == 0) ? Qo : Ko;
#pragma unroll
        for (int mi = 0; mi < 4; ++mi)
#pragma unroll
            for (int ni = 0; ni < 4; ++ni) {
                const int n = n0 + wn + ni * 16 + l16;
                const float bn = bias[n];
                const int dk = n & 63;
                const int cc = dk >> 3, ee = dk & 7;
                const size_t hb = (size_t)(n >> 6) * S_LEN * DK;
#pragma unroll
                for (int r = 0; r < 4; ++r) {
                    const int m = m0 + wm + mi * 16 + quad * 4 + r;
                    const int pdk = ((cc ^ (m & 7)) << 3) | ee;   // XOR swizzle by s-row
                    out[hb + (size_t)m * DK + pdk] = (bf16)((acc[mi][ni][r] + bn) * scale);
                }
            }
    } else {
        // V^T tiled: Vo[h][T][dk][64], 8-elem chunk (tt>>3) swizzled by ^(dk&7)
#pragma unroll
        for (int mi = 0; mi < 4; ++mi)
#pragma unroll
            for (int ni = 0; ni < 4; ++ni) {
                const int n = n0 + wn + ni * 16 + l16;     // h*64 + dk
                const float bn = bias[n];
                const int dk = n & 63;
                const size_t hb = (size_t)(n >> 6) * (64 * S_LEN);
                const int mbase = m0 + wm + mi * 16 + quad * 4;   // t, 4 contiguous
                const int T  = mbase >> 6;
                const int tt = mbase & 63;
                const int pos = (((tt >> 3) ^ (dk & 7)) << 3) | (tt & 7);
                bf16x4 r4;
#pragma unroll
                for (int r = 0; r < 4; ++r) r4[r] = (bf16)(acc[mi][ni][r] + bn);
                *(bf16x4*)&Vo[hb + (size_t)T * 4096 + dk * 64 + pos] = r4;
            }
    }
}

// Output GEMM, 64x128 tile (512 blocks = 2/CU), r9-proven.
__global__ void __launch_bounds__(256) gemm_out(
    const bf16* __restrict__ A, const bf16* __restrict__ Bw,
    const float* __restrict__ bias, float* __restrict__ out)
{
    __shared__ __align__(16) bf16 As[64 * 32];    // 4 KB
    __shared__ __align__(16) bf16 Bs[128 * 32];   // 8 KB

    const int tid  = threadIdx.x;
    const int wave = tid >> 6;
    const int lane = tid & 63;
    const int quad = lane >> 4;
    const int l16  = lane & 15;
    const int m0 = blockIdx.x * 64;
    const int n0 = blockIdx.y * 128;
    const int wm = (wave & 1) * 32;
    const int wn = (wave >> 1) * 64;

    const int srow = tid >> 2;
    const int scol = (tid & 3) * 8;
    const bf16* Ag  = A  + (size_t)(m0 + srow) * DMODEL + scol;
    const bf16* Bg  = Bw + (size_t)(n0 + srow) * DMODEL + scol;
    const bf16* Bg2 = Bg + (size_t)64 * DMODEL;

    f32x4 acc[2][4] = {};
    for (int k0 = 0; k0 < DMODEL; k0 += 32) {
        async16(Ag,  (char*)As + wave * 1024);
        async16(Bg,  (char*)Bs + wave * 1024);
        async16(Bg2, (char*)Bs + 4096 + wave * 1024);
        Ag += 32; Bg += 32; Bg2 += 32;
        __syncthreads();

        bf16x8 af[2], bfr[4];
#pragma unroll
        for (int i = 0; i < 2; ++i)
            af[i] = *(const bf16x8*)&As[(wm + i * 16 + l16) * 32 + quad * 8];
#pragma unroll
        for (int i = 0; i < 4; ++i)
            bfr[i] = *(const bf16x8*)&Bs[(wn + i * 16 + l16) * 32 + quad * 8];

#pragma unroll
        for (int mi = 0; mi < 2; ++mi)
#pragma unroll
            for (int ni = 0; ni < 4; ++ni)
                acc[mi][ni] = __builtin_amdgcn_mfma_f32_16x16x32_bf16(
                    af[mi], bfr[ni], acc[mi][ni], 0, 0, 0);
        __syncthreads();
    }

#pragma unroll
    for (int mi = 0; mi < 2; ++mi)
#pragma unroll
        for (int ni = 0; ni < 4; ++ni) {
            const int n = n0 + wn + ni * 16 + l16;
            const float bn = bias[n];
#pragma unroll
            for (int r = 0; r < 4; ++r) {
                const int m = m0 + wm + mi * 16 + quad * 4 + r;
                out[(size_t)m * DMODEL + n] = acc[mi][ni][r] + bn;
            }
        }
}

// ---------------------------------------------------------------------------
// Flash attention — ROUND-6: KV-split x2 for TLP (4 waves/SIMD).
//
//  Why: r5 counters show NO saturated pipe (Mfma 32, VALU 41, DS ~46%,
//  staging ~50%) at 2 waves/SIMD — issue-slot shortage from serial per-wave
//  chains. KV-split: blockIdx.z in {0,1} selects t-range half (2048 rows,
//  32 iters). Grid 512 blocks = 2 blocks/CU (LDS 80 KB x2 = 160 exactly) =
//  16 waves/CU = 4/SIMD. Per-CU staged bytes UNCHANGED (each block stages
//  only its half-range) — does not regress to r3's staging-bound regime.
//
//  Softmax has no running max (pure exp2 of pre-scaled scores), so halves
//  are directly addable: blocks atomicAdd unnormalized O (f32) + partial
//  denominator into a zeroed accumulator; combine kernel normalizes -> CTX.
//  Order-independent => safe under undefined dispatch order (G16); f32
//  atomics are device-scope by default (m20).
//
//  Per-wave structure unchanged from r5 (8 waves x 32 q-rows, 32x32x16 MFMA,
//  in-register P via pk2+permlane32, 3-buffer ring + counted vmcnt).
// ---------------------------------------------------------------------------
__global__ void __launch_bounds__(512) flash_attn(
    const bf16* __restrict__ Q, const bf16* __restrict__ Kh,
    const bf16* __restrict__ Vt, float* __restrict__ accO,
    float* __restrict__ lsums)
{
    __shared__ __align__(16) bf16 Qs[256 * 64];      // 32 KB
    __shared__ __align__(16) bf16 Ks[3][64 * 64];    // 24 KB (3-ring)
    __shared__ __align__(16) bf16 Vs[3][64 * 64];    // 24 KB (3-ring)

    const int tid  = threadIdx.x;
    const int wave = tid >> 6;           // 0..7
    const int lane = tid & 63;
    const int l31  = lane & 31;
    const int hi   = lane >> 5;          // 0 = lanes 0..31, 1 = lanes 32..63
    const int x7   = lane & 7;           // row&7 swizzle key (row = *&31)
    const int s0 = blockIdx.x * 256;
    const int h  = blockIdx.y;
    const int z  = blockIdx.z;           // K/V half: t in [z*2048, z*2048+2048)

    const bf16* Kg = Kh + (size_t)h * S_LEN * DK + (size_t)z * 2048 * DK + tid * 8;
    const bf16* Vg = Vt + (size_t)h * (64 * S_LEN) + (size_t)z * 32 * 4096 + tid * 8;

    // prologue: stage Q tile (32 KB) + K/V tiles 0 and 1
    {
        const bf16* Qg = Q + (size_t)h * S_LEN * DK + (size_t)s0 * DK + tid * 8;
#pragma unroll
        for (int j = 0; j < 4; ++j)
            async16(Qg + j * 4096, (char*)Qs + j * 8192 + wave * 1024);
    }
    async16(Kg, (char*)Ks + wave * 1024);
    async16(Vg, (char*)Vs + wave * 1024);
    Kg += 4096; Vg += 4096;
    async16(Kg, (char*)Ks + 8192 + wave * 1024);
    async16(Vg, (char*)Vs + 8192 + wave * 1024);
    Kg += 4096; Vg += 4096;
    // wait Q + tile0 (tile1's 2 loads may remain in flight), then barrier
    asm volatile("s_waitcnt vmcnt(2)" ::: "memory");
    __builtin_amdgcn_s_barrier();
    __builtin_amdgcn_sched_barrier(0);

    // Q B-fragments: qf[ks] = Q[s = wave*32 + l31][k = ks*16 + hi*8 + 0..7]
    bf16x8 qf[4];
    {
        const bf16* qb = &Qs[(wave * 32 + l31) * 64];
#pragma unroll
        for (int ks = 0; ks < 4; ++ks)
            qf[ks] = *(const bf16x8*)(qb + ((((ks << 1) + hi) ^ x7) << 3));
    }

    f32x16 od[2] = {};
    float lsum = 0.0f;

    // per-tile compute from ring buffer cb (reads Ks[cb]/Vs[cb], accumulates od/lsum)
    auto compute = [&](int cb) {
        const bf16* Kc = &Ks[cb][0];
        const bf16* Vc = &Vs[cb][0];

        f32x16 st[2] = {};
        __builtin_amdgcn_s_setprio(1);
#pragma unroll
        for (int tt = 0; tt < 2; ++tt) {
            const bf16* kb = &Kc[(tt * 32 + l31) * 64];
#pragma unroll
            for (int ks = 0; ks < 4; ++ks) {
                bf16x8 kf = *(const bf16x8*)(kb + ((((ks << 1) + hi) ^ x7) << 3));
                st[tt] = __builtin_amdgcn_mfma_f32_32x32x16_bf16(kf, qf[ks], st[tt], 0, 0, 0);
            }
        }
        __builtin_amdgcn_s_setprio(0);

        // softmax-lite + in-register P->B-frag build.
        bf16x8 pf[4];
#pragma unroll
        for (int tt = 0; tt < 2; ++tt) {
            float p[16];
#pragma unroll
            for (int r = 0; r < 16; ++r) {
                p[r] = fast_exp2(st[tt][r]);
                lsum += p[r];
            }
#pragma unroll
            for (int w = 0; w < 2; ++w) {
                const int G = w * 8;
                unsigned A0 = pk2(p[G + 0], p[G + 1]);
                unsigned A1 = pk2(p[G + 2], p[G + 3]);
                unsigned B0 = pk2(p[G + 4], p[G + 5]);
                unsigned B1 = pk2(p[G + 6], p[G + 7]);
                pl32swap(A0, B0);
                pl32swap(A1, B1);
                pf[tt * 2 + w] = mkfrag(A0, A1, B0, B1);
            }
        }

        // O^T += V^T_frag * P_frag
        __builtin_amdgcn_s_setprio(1);
#pragma unroll
        for (int dd = 0; dd < 2; ++dd) {
            const bf16* vb = &Vc[(dd * 32 + l31) * 64];
#pragma unroll
            for (int ks = 0; ks < 4; ++ks) {
                bf16x8 vf = *(const bf16x8*)(vb + ((((ks << 1) + hi) ^ x7) << 3));
                od[dd] = __builtin_amdgcn_mfma_f32_32x32x16_bf16(vf, pf[ks], od[dd], 0, 0, 0);
            }
        }
        __builtin_amdgcn_s_setprio(0);
    };

    int cur = 0;
    for (int it = 0; it < 30; ++it) {
        // prefetch tile it+2 into ring slot (cur+2)%3
        int nb = cur + 2; if (nb >= 3) nb -= 3;
        async16(Kg, (char*)Ks + nb * 8192 + wave * 1024);
        async16(Vg, (char*)Vs + nb * 8192 + wave * 1024);
        Kg += 4096; Vg += 4096;

        compute(cur);

        // counted sync: only this iter's 2 loads may remain in flight.
        asm volatile("s_waitcnt vmcnt(2)" ::: "memory");
        __builtin_amdgcn_s_barrier();
        __builtin_amdgcn_sched_barrier(0);
        cur = (cur + 1 == 3) ? 0 : cur + 1;
    }
    // tile 30: no prefetch left; tile 31's loads (issued at it=29) must land.
    compute(cur);
    asm volatile("s_waitcnt vmcnt(0)" ::: "memory");
    __builtin_amdgcn_s_barrier();
    __builtin_amdgcn_sched_barrier(0);
    cur = (cur + 1 == 3) ? 0 : cur + 1;
    // tile 31: last compute, no sync needed after (epilogue is per-wave).
    compute(cur);

    // epilogue: atomic-accumulate UNNORMALIZED od + partial lsum (f32).
    // lane owns s-col = s0 + wave*32 + l31, d = dd*32 + g*8 + hi*4 + r.
    // acc layout is the logical [s][h*64+d] (same linear index as CTX).
    const int s = s0 + wave * 32 + l31;
    atomicAdd(&lsums[s * NHEADS + h], lsum);
    float* base = accO + (size_t)s * DMODEL + h * DK;
#pragma unroll
    for (int dd = 0; dd < 2; ++dd)
#pragma unroll
        for (int g = 0; g < 4; ++g)
#pragma unroll
            for (int r = 0; r < 4; ++r)
                atomicAdd(&base[dd * 32 + g * 8 + hi * 4 + r], od[dd][g * 4 + r]);
}

// ---------------------------------------------------------------------------
// Combine: CTX[s][h*64+d] = accO[s][h*64+d] / lsums[s][h].  acc linear index
// equals CTX linear index; one f32x4 per thread.
// ---------------------------------------------------------------------------
__global__ void __launch_bounds__(256) combine(
    const float* __restrict__ accO, const float* __restrict__ lsums,
    bf16* __restrict__ ctx)
{
    const int idx = blockIdx.x * 256 + threadIdx.x;   // f32x4 group, ACT/4 total
    float4 a = ((const float4*)accO)[idx];
    // group idx covers elements e = idx*4 .. idx*4+3, all same (s,h):
    // e/64 = s*16 + h  (since DMODEL/DK = 16 groups of 64 per row)
    const float rinv = 1.0f / lsums[idx >> 4];
    bf16x4 r = { (bf16)(a.x * rinv), (bf16)(a.y * rinv),
                 (bf16)(a.z * rinv), (bf16)(a.w * rinv) };
    ((bf16x4*)ctx)[idx] = r;
}

// ---------------------------------------------------------------------------
extern "C" void kernel_launch(void* const* d_in, const int* in_sizes, int n_in,
                              void* d_out, int out_size, void* d_ws, size_t ws_size,
                              hipStream_t stream)
{
    (void)in_sizes; (void)n_in; (void)out_size; (void)ws_size;
    const float* q  = (const float*)d_in[0];
    const float* k  = (const float*)d_in[1];
    const float* v  = (const float*)d_in[2];
    const float* Wq = (const float*)d_in[3];
    const float* bq = (const float*)d_in[4];
    const float* Wk = (const float*)d_in[5];
    const float* bk = (const float*)d_in[6];
    const float* Wv = (const float*)d_in[7];
    const float* bv = (const float*)d_in[8];
    const float* Wo = (const float*)d_in[9];
    const float* bo = (const float*)d_in[10];

    // workspace layout (bf16), total exactly 64 MB
    bf16* Xq  = (bf16*)d_ws;
    bf16* Xk  = Xq  + ACT;
    bf16* Xv  = Xk  + ACT;
    bf16* Wqb = Xv  + ACT;
    bf16* Wkb = Wqb + WELE;
    bf16* Wvb = Wkb + WELE;
    bf16* Wob = Wvb + WELE;
    bf16* Qh  = Wob + WELE;  // [h][s][dk] swizzled
    bf16* Kh  = Qh  + ACT;   // [h][t][dk] swizzled
    bf16* Vt  = Kh  + ACT;   // [h][T][dk][64] swizzled, tiled
    bf16* CTX = Vt  + ACT;   // [s][1024]

    // f32 flash accumulators overlay Xq/Xk/Xv (dead after proj_qkv):
    //   accO: ACT f32 = 16.78 MB; lsums: S*H f32 = 0.26 MB. Total 17 MB < 24.
    float* accO  = (float*)d_ws;
    float* lsums = accO + ACT;

    cvt7<<<dim3(ACT / 4 / 256, 7), 256, 0, stream>>>(
        q, k, v, Wq, Wk, Wv, Wo,
        Xq, Xk, Xv, Wqb, Wkb, Wvb, Wob, ACT / 4, WELE / 4);

    const float qscale = 0.125f * 1.4426950408889634f;  // 1/sqrt(Dk) * log2(e)
    proj_qkv<<<dim3(S_LEN / 128, DMODEL / 128, 3), 256, 0, stream>>>(
        Xq, Wqb, bq, Qh, Xk, Wkb, bk, Kh, Xv, Wvb, bv, Vt, qscale);

    // zero the atomic accumulators (stream-ordered; graph-capture-safe)
    hipMemsetAsync(accO, 0, (size_t)(ACT + S_LEN * NHEADS) * sizeof(float), stream);

    flash_attn<<<dim3(S_LEN / 256, NHEADS, 2), 512, 0, stream>>>(
        Qh, Kh, Vt, accO, lsums);

    combine<<<dim3(ACT / 4 / 256), 256, 0, stream>>>(accO, lsums, CTX);

    gemm_out<<<dim3(S_LEN / 64, DMODEL / 128), 256, 0, stream>>>(CTX, Wob, bo, (float*)d_out);
}

// Round 7
// 256.105 us; speedup vs baseline: 1.8283x; 1.8283x over previous
//
#include <hip/hip_runtime.h>
#include <cstdint>
#include <cstddef>

// Problem dims (fixed): B=1, S=4096, D_MODEL=1024, H=16, Dk=64.
#define S_LEN 4096
#define DMODEL 1024
#define NHEADS 16
#define DK 64
#define ACT (S_LEN * DMODEL)     // 4,194,304 elements
#define WELE (DMODEL * DMODEL)   // 1,048,576 elements

typedef __bf16 bf16;
typedef bf16  bf16x2 __attribute__((ext_vector_type(2)));
typedef bf16  bf16x4 __attribute__((ext_vector_type(4)));
typedef bf16  bf16x8 __attribute__((ext_vector_type(8)));
typedef float f32x4  __attribute__((ext_vector_type(4)));
typedef float f32x16 __attribute__((ext_vector_type(16)));
typedef unsigned int uint32x4v __attribute__((ext_vector_type(4)));

// ---- async global->LDS, 16B per lane, offset 0 only. LDS dest = wave-uniform
// base + lane*16. (Round-3-proven form.)
__device__ __forceinline__ void async16(const void* g, void* l) {
    __builtin_amdgcn_global_load_lds(
        (__attribute__((address_space(1))) void*)(uintptr_t)g,
        (__attribute__((address_space(3))) void*)(uintptr_t)l,
        16, 0, 0);
}

__device__ __forceinline__ float fast_exp2(float x) {
#if __has_builtin(__builtin_amdgcn_exp2f)
    return __builtin_amdgcn_exp2f(x);
#else
    return exp2f(x);
#endif
}

// pack two f32 -> one dword of 2 bf16 (compiler emits cvt + pack; m240: do
// NOT hand-write v_cvt_pk_bf16_f32)
__device__ __forceinline__ unsigned pk2(float a, float b) {
    bf16x2 t; t[0] = (bf16)a; t[1] = (bf16)b;
    return __builtin_bit_cast(unsigned, t);
}

// v_permlane32_swap_b32: swaps a's upper 32 lanes with b's lower 32 lanes.
__device__ __forceinline__ void pl32swap(unsigned &a, unsigned &b) {
    asm volatile("v_permlane32_swap_b32 %0, %1" : "+v"(a), "+v"(b));
}

__device__ __forceinline__ bf16x8 mkfrag(unsigned w0, unsigned w1, unsigned w2, unsigned w3) {
    uint32x4v u = { w0, w1, w2, w3 };
    return __builtin_bit_cast(bf16x8, u);
}

// ---------------------------------------------------------------------------
// fp32 -> bf16 converter, 7 tensors in one launch (y = 0..6).
// ---------------------------------------------------------------------------
__global__ void __launch_bounds__(256) cvt7(
    const float* a0, const float* a1, const float* a2,
    const float* w0, const float* w1, const float* w2, const float* w3,
    bf16* oa0, bf16* oa1, bf16* oa2,
    bf16* ow0, bf16* ow1, bf16* ow2, bf16* ow3,
    int nA, int nB)
{
    const float* s; bf16* d; int n4;
    switch (blockIdx.y) {
        case 0: s = a0; d = oa0; n4 = nA; break;
        case 1: s = a1; d = oa1; n4 = nA; break;
        case 2: s = a2; d = oa2; n4 = nA; break;
        case 3: s = w0; d = ow0; n4 = nB; break;
        case 4: s = w1; d = ow1; n4 = nB; break;
        case 5: s = w2; d = ow2; n4 = nB; break;
        default: s = w3; d = ow3; n4 = nB; break;
    }
    int i = blockIdx.x * 256 + threadIdx.x;
    if (i < n4) {
        float4 v = ((const float4*)s)[i];
        bf16x4 r = { (bf16)v.x, (bf16)v.y, (bf16)v.z, (bf16)v.w };
        ((bf16x4*)d)[i] = r;
    }
}

// ---------------------------------------------------------------------------
// MFMA sub-tile compute on a [128][32] LDS tile pair (r8-proven layout).
// ---------------------------------------------------------------------------
__device__ __forceinline__ void gemm_compute_128(
    const bf16* As, const bf16* Bs, f32x4 (&acc)[4][4],
    int wm, int wn, int l16, int quad)
{
    bf16x8 af[4], bfr[4];
#pragma unroll
    for (int i = 0; i < 4; ++i)
        af[i] = *(const bf16x8*)&As[(wm + i * 16 + l16) * 32 + quad * 8];
#pragma unroll
    for (int i = 0; i < 4; ++i)
        bfr[i] = *(const bf16x8*)&Bs[(wn + i * 16 + l16) * 32 + quad * 8];
#pragma unroll
    for (int mi = 0; mi < 4; ++mi)
#pragma unroll
        for (int ni = 0; ni < 4; ++ni)
            acc[mi][ni] = __builtin_amdgcn_mfma_f32_16x16x32_bf16(
                af[mi], bfr[ni], acc[mi][ni], 0, 0, 0);
}

// NT GEMM core, BK=64 as two proven BK=32 sub-tiles per barrier pair.
__device__ __forceinline__ void gemm_core_bk64(
    const bf16* __restrict__ A, const bf16* __restrict__ B,
    bf16* As, bf16* Bs, f32x4 (&acc)[4][4],
    int m0, int n0, int wm, int wn, int K)
{
    const int tid  = threadIdx.x;
    const int wave = tid >> 6;
    const int lane = tid & 63;
    const int quad = lane >> 4;
    const int l16  = lane & 15;

    const int srow = tid >> 2;
    const int scol = (tid & 3) * 8;
    const bf16* Ag = A + (size_t)(m0 + srow) * K + scol;
    const bf16* Bg = B + (size_t)(n0 + srow) * K + scol;
    char* lA = (char*)As + wave * 1024;
    char* lB = (char*)Bs + wave * 1024;

    for (int k0 = 0; k0 < K; k0 += 64) {
        async16(Ag,                       lA);
        async16(Ag + (size_t)64 * K,      lA + 4096);
        async16(Ag + 32,                  lA + 8192);
        async16(Ag + 32 + (size_t)64 * K, lA + 12288);
        async16(Bg,                       lB);
        async16(Bg + (size_t)64 * K,      lB + 4096);
        async16(Bg + 32,                  lB + 8192);
        async16(Bg + 32 + (size_t)64 * K, lB + 12288);
        Ag += 64; Bg += 64;
        __syncthreads();

        gemm_compute_128(As,        Bs,        acc, wm, wn, l16, quad);
        gemm_compute_128(As + 4096, Bs + 4096, acc, wm, wn, l16, quad);
        __syncthreads();
    }
}

// Fused QKV projection (r8 epilogues). blockIdx.z selects {Q,K,V}.
// Q/K: head-major bf16 [h][s][dk], 16B-chunk XOR-swizzled by (s&7) per row.
// V:   transposed TILED bf16 [h][T=t/64][dk][64], chunk-swizzled by (dk&7).
// Q pre-scaled by 0.125*log2e.
__global__ void __launch_bounds__(256) proj_qkv(
    const bf16* __restrict__ Xq, const bf16* __restrict__ Wq, const float* __restrict__ bq, bf16* __restrict__ Qo,
    const bf16* __restrict__ Xk, const bf16* __restrict__ Wk, const float* __restrict__ bk, bf16* __restrict__ Ko,
    const bf16* __restrict__ Xv, const bf16* __restrict__ Wv, const float* __restrict__ bv, bf16* __restrict__ Vo,
    float qscale)
{
    __shared__ __align__(16) bf16 As[2 * 128 * 32];   // 16 KB
    __shared__ __align__(16) bf16 Bs[2 * 128 * 32];   // 16 KB

    const int which = blockIdx.z;
    const bf16*  A    = (which == 0) ? Xq : (which == 1) ? Xk : Xv;
    const bf16*  Bw   = (which == 0) ? Wq : (which == 1) ? Wk : Wv;
    const float* bias = (which == 0) ? bq : (which == 1) ? bk : bv;
    const float  scale = (which == 0) ? qscale : 1.0f;

    const int tid  = threadIdx.x;
    const int wave = tid >> 6;
    const int lane = tid & 63;
    const int quad = lane >> 4;
    const int l16  = lane & 15;
    const int m0 = blockIdx.x * 128;
    const int n0 = blockIdx.y * 128;
    const int wm = (wave & 1) * 64;
    const int wn = (wave >> 1) * 64;

    f32x4 acc[4][4] = {};
    gemm_core_bk64(A, Bw, As, Bs, acc, m0, n0, wm, wn, DMODEL);

    // C/D layout: col(n) = lane&15, row(m) = quad*4 + reg
    if (which < 2) {
        bf16* out = (which == 0) ? Qo : Ko;
#pragma unroll
        for (int mi = 0; mi < 4; ++mi)
#pragma unroll
            for (int ni = 0; ni < 4; ++ni) {
                const int n = n0 + wn + ni * 16 + l16;
                const float bn = bias[n];
                const int dk = n & 63;
                const int cc = dk >> 3, ee = dk & 7;
                const size_t hb = (size_t)(n >> 6) * S_LEN * DK;
#pragma unroll
                for (int r = 0; r < 4; ++r) {
                    const int m = m0 + wm + mi * 16 + quad * 4 + r;
                    const int pdk = ((cc ^ (m & 7)) << 3) | ee;   // XOR swizzle by s-row
                    out[hb + (size_t)m * DK + pdk] = (bf16)((acc[mi][ni][r] + bn) * scale);
                }
            }
    } else {
        // V^T tiled: Vo[h][T][dk][64], 8-elem chunk (tt>>3) swizzled by ^(dk&7)
#pragma unroll
        for (int mi = 0; mi < 4; ++mi)
#pragma unroll
            for (int ni = 0; ni < 4; ++ni) {
                const int n = n0 + wn + ni * 16 + l16;     // h*64 + dk
                const float bn = bias[n];
                const int dk = n & 63;
                const size_t hb = (size_t)(n >> 6) * (64 * S_LEN);
                const int mbase = m0 + wm + mi * 16 + quad * 4;   // t, 4 contiguous
                const int T  = mbase >> 6;
                const int tt = mbase & 63;
                const int pos = (((tt >> 3) ^ (dk & 7)) << 3) | (tt & 7);
                bf16x4 r4;
#pragma unroll
                for (int r = 0; r < 4; ++r) r4[r] = (bf16)(acc[mi][ni][r] + bn);
                *(bf16x4*)&Vo[hb + (size_t)T * 4096 + dk * 64 + pos] = r4;
            }
    }
}

// Output GEMM, 64x128 tile (512 blocks = 2/CU), r9-proven.
__global__ void __launch_bounds__(256) gemm_out(
    const bf16* __restrict__ A, const bf16* __restrict__ Bw,
    const float* __restrict__ bias, float* __restrict__ out)
{
    __shared__ __align__(16) bf16 As[64 * 32];    // 4 KB
    __shared__ __align__(16) bf16 Bs[128 * 32];   // 8 KB

    const int tid  = threadIdx.x;
    const int wave = tid >> 6;
    const int lane = tid & 63;
    const int quad = lane >> 4;
    const int l16  = lane & 15;
    const int m0 = blockIdx.x * 64;
    const int n0 = blockIdx.y * 128;
    const int wm = (wave & 1) * 32;
    const int wn = (wave >> 1) * 64;

    const int srow = tid >> 2;
    const int scol = (tid & 3) * 8;
    const bf16* Ag  = A  + (size_t)(m0 + srow) * DMODEL + scol;
    const bf16* Bg  = Bw + (size_t)(n0 + srow) * DMODEL + scol;
    const bf16* Bg2 = Bg + (size_t)64 * DMODEL;

    f32x4 acc[2][4] = {};
    for (int k0 = 0; k0 < DMODEL; k0 += 32) {
        async16(Ag,  (char*)As + wave * 1024);
        async16(Bg,  (char*)Bs + wave * 1024);
        async16(Bg2, (char*)Bs + 4096 + wave * 1024);
        Ag += 32; Bg += 32; Bg2 += 32;
        __syncthreads();

        bf16x8 af[2], bfr[4];
#pragma unroll
        for (int i = 0; i < 2; ++i)
            af[i] = *(const bf16x8*)&As[(wm + i * 16 + l16) * 32 + quad * 8];
#pragma unroll
        for (int i = 0; i < 4; ++i)
            bfr[i] = *(const bf16x8*)&Bs[(wn + i * 16 + l16) * 32 + quad * 8];

#pragma unroll
        for (int mi = 0; mi < 2; ++mi)
#pragma unroll
            for (int ni = 0; ni < 4; ++ni)
                acc[mi][ni] = __builtin_amdgcn_mfma_f32_16x16x32_bf16(
                    af[mi], bfr[ni], acc[mi][ni], 0, 0, 0);
        __syncthreads();
    }

#pragma unroll
    for (int mi = 0; mi < 2; ++mi)
#pragma unroll
        for (int ni = 0; ni < 4; ++ni) {
            const int n = n0 + wn + ni * 16 + l16;
            const float bn = bias[n];
#pragma unroll
            for (int r = 0; r < 4; ++r) {
                const int m = m0 + wm + mi * 16 + quad * 4 + r;
                out[(size_t)m * DMODEL + n] = acc[mi][ni][r] + bn;
            }
        }
}

// ---------------------------------------------------------------------------
// Flash attention — ROUND-7: 64 q-rows per wave + KV-split with NON-atomic
// f32 partial buffers.
//
//  Why: r5 per-CU DS accounting: 8 waves x 16 b128 x 12cyc + 513 conflict-cyc
//  + staging writes = ~2250 of 3337-cyc window (67%) — DS-amplification (all
//  waves read the whole K/V tile) is the near-saturated pipe, plus serial
//  per-wave chains at 2 waves/SIMD. r6 showed the compute core intact but
//  atomics poisoned the epilogue (8.7M atomicAdds).
//
//  Fix: (1) each wave owns TWO 32-row q-groups: each K/V fragment read feeds
//  2 MFMAs -> DS reads per unit work halved, per-wave ILP doubled (2
//  independent st/od chains). (2) KV-split z in {0,1}, 4-wave 256-thread
//  blocks, grid (16,16,2)=512 = 2 blocks/CU = 2 waves/SIMD (TLP kept).
//  (3) partial O written f32 NON-atomically to per-z buffers; combine sums
//  halves + normalizes -> bf16 (same math as r5: f32 sums, one bf16 round).
//
//  LDS = Qs 32K + K dbuf 16K + V dbuf 16K = 64 KB -> 2 blocks/CU guaranteed.
//  Staging: r4-proven dbuf (prefetch next before compute, __syncthreads).
//  VGPR pinned <=256 via __launch_bounds__(256,2).
// ---------------------------------------------------------------------------
__global__ void __launch_bounds__(256, 2) flash_attn(
    const bf16* __restrict__ Q, const bf16* __restrict__ Kh,
    const bf16* __restrict__ Vt,
    float* __restrict__ O0, float* __restrict__ O1lo, float* __restrict__ O1hi,
    float* __restrict__ lsums)
{
    __shared__ __align__(16) bf16 Qs[256 * 64];      // 32 KB
    __shared__ __align__(16) bf16 Ks[2][64 * 64];    // 16 KB (dbuf)
    __shared__ __align__(16) bf16 Vs[2][64 * 64];    // 16 KB (dbuf)

    const int tid  = threadIdx.x;
    const int wave = tid >> 6;           // 0..3
    const int lane = tid & 63;
    const int l31  = lane & 31;
    const int hi   = lane >> 5;          // 0 = lanes 0..31, 1 = lanes 32..63
    const int x7   = lane & 7;           // row&7 swizzle key (row = *&31)
    const int s0 = blockIdx.x * 256;
    const int h  = blockIdx.y;
    const int z  = blockIdx.z;           // K/V half: t in [z*2048, z*2048+2048)

    const bf16* Kg = Kh + (size_t)h * S_LEN * DK + (size_t)z * 2048 * DK + tid * 8;
    const bf16* Vg = Vt + (size_t)h * (64 * S_LEN) + (size_t)z * 32 * 4096 + tid * 8;

    // prologue: stage Q tile (32 KB, 8 rounds of 4 KB) + K/V tile 0 (2 rounds each)
    {
        const bf16* Qg = Q + (size_t)h * S_LEN * DK + (size_t)s0 * DK + tid * 8;
#pragma unroll
        for (int j = 0; j < 8; ++j)
            async16(Qg + j * 2048, (char*)Qs + j * 4096 + wave * 1024);
    }
    async16(Kg,        (char*)Ks + wave * 1024);
    async16(Kg + 2048, (char*)Ks + 4096 + wave * 1024);
    async16(Vg,        (char*)Vs + wave * 1024);
    async16(Vg + 2048, (char*)Vs + 4096 + wave * 1024);
    Kg += 4096; Vg += 4096;
    __syncthreads();

    // Q B-fragments, 2 groups: qf[g][ks] = Q[s = wave*64 + g*32 + l31][ks*16 + hi*8 + 0..7]
    bf16x8 qf[2][4];
#pragma unroll
    for (int g = 0; g < 2; ++g) {
        const bf16* qb = &Qs[(wave * 64 + g * 32 + l31) * 64];
#pragma unroll
        for (int ks = 0; ks < 4; ++ks)
            qf[g][ks] = *(const bf16x8*)(qb + ((((ks << 1) + hi) ^ x7) << 3));
    }

    f32x16 od[2][2] = {};     // [g][dd]
    float lsum[2] = {};       // [g]
    int cur = 0;

    for (int it = 0; it < 32; ++it) {
        // prefetch NEXT K/V tile into the other buffer (overlaps with compute)
        if (it < 31) {
            char* lK = (char*)Ks + (cur ^ 1) * 8192 + wave * 1024;
            char* lV = (char*)Vs + (cur ^ 1) * 8192 + wave * 1024;
            async16(Kg,        lK);
            async16(Kg + 2048, lK + 4096);
            async16(Vg,        lV);
            async16(Vg + 2048, lV + 4096);
            Kg += 4096; Vg += 4096;
        }
        const bf16* Kc = &Ks[cur][0];
        const bf16* Vc = &Vs[cur][0];

        // S^T tiles, shared K-frag reads: st[g][tt]
        f32x16 st[2][2] = {};
        __builtin_amdgcn_s_setprio(1);
#pragma unroll
        for (int tt = 0; tt < 2; ++tt) {
            const bf16* kb = &Kc[(tt * 32 + l31) * 64];
#pragma unroll
            for (int ks = 0; ks < 4; ++ks) {
                bf16x8 kf = *(const bf16x8*)(kb + ((((ks << 1) + hi) ^ x7) << 3));
                st[0][tt] = __builtin_amdgcn_mfma_f32_32x32x16_bf16(kf, qf[0][ks], st[0][tt], 0, 0, 0);
                st[1][tt] = __builtin_amdgcn_mfma_f32_32x32x16_bf16(kf, qf[1][ks], st[1][tt], 0, 0, 0);
            }
        }
        __builtin_amdgcn_s_setprio(0);

        // softmax-lite + in-register P->B-frag build, per group.
        bf16x8 pf[2][4];
#pragma unroll
        for (int g = 0; g < 2; ++g)
#pragma unroll
            for (int tt = 0; tt < 2; ++tt) {
                float p[16];
#pragma unroll
                for (int r = 0; r < 16; ++r) {
                    p[r] = fast_exp2(st[g][tt][r]);
                    lsum[g] += p[r];
                }
#pragma unroll
                for (int w = 0; w < 2; ++w) {
                    const int G = w * 8;
                    unsigned A0 = pk2(p[G + 0], p[G + 1]);
                    unsigned A1 = pk2(p[G + 2], p[G + 3]);
                    unsigned B0 = pk2(p[G + 4], p[G + 5]);
                    unsigned B1 = pk2(p[G + 6], p[G + 7]);
                    pl32swap(A0, B0);
                    pl32swap(A1, B1);
                    pf[g][tt * 2 + w] = mkfrag(A0, A1, B0, B1);
                }
            }

        // O^T += V^T_frag * P_frag, shared V-frag reads
        __builtin_amdgcn_s_setprio(1);
#pragma unroll
        for (int dd = 0; dd < 2; ++dd) {
            const bf16* vb = &Vc[(dd * 32 + l31) * 64];
#pragma unroll
            for (int ks = 0; ks < 4; ++ks) {
                bf16x8 vf = *(const bf16x8*)(vb + ((((ks << 1) + hi) ^ x7) << 3));
                od[0][dd] = __builtin_amdgcn_mfma_f32_32x32x16_bf16(vf, pf[0][ks], od[0][dd], 0, 0, 0);
                od[1][dd] = __builtin_amdgcn_mfma_f32_32x32x16_bf16(vf, pf[1][ks], od[1][dd], 0, 0, 0);
            }
        }
        __builtin_amdgcn_s_setprio(0);

        __syncthreads();   // protects buf[cur] before restage; drains prefetch
        cur ^= 1;
    }

    // epilogue: NON-atomic f32 partial writes. Partial-O buffer for this z:
    //   z=0: O0 (contiguous);  z=1: O1lo covers s<2048, O1hi covers s>=2048.
    float* Ob = (z == 0) ? O0
              : (s0 < 2048 ? O1lo : O1hi - (size_t)2048 * DMODEL);
    float* lz = lsums + (size_t)z * S_LEN * NHEADS;
#pragma unroll
    for (int g = 0; g < 2; ++g) {
        float ls = lsum[g] + __shfl_xor(lsum[g], 32);
        const int s = s0 + wave * 64 + g * 32 + l31;
        if (hi == 0) lz[s * NHEADS + h] = ls;
        float* bp = Ob + (size_t)s * DMODEL + h * DK;
#pragma unroll
        for (int dd = 0; dd < 2; ++dd)
#pragma unroll
            for (int gg = 0; gg < 4; ++gg) {
                f32x4 r4 = { od[g][dd][gg * 4 + 0], od[g][dd][gg * 4 + 1],
                             od[g][dd][gg * 4 + 2], od[g][dd][gg * 4 + 3] };
                *(f32x4*)&bp[dd * 32 + gg * 8 + hi * 4] = r4;
            }
    }
}

// ---------------------------------------------------------------------------
// Combine: ctxn[s][dm] = (O0 + O1) / (l0 + l1), bf16. One f32x4 per thread;
// each 256-thread block covers exactly one s-row (s uniform per block).
// ---------------------------------------------------------------------------
__global__ void __launch_bounds__(256) combine(
    const float* __restrict__ O0, const float* __restrict__ O1lo,
    const float* __restrict__ O1hi, const float* __restrict__ lsums,
    bf16* __restrict__ ctxn)
{
    const int idx = blockIdx.x * 256 + threadIdx.x;   // f32x4 group, ACT/4 total
    const int s = idx >> 8;                           // 256 groups per s-row
    float4 a = ((const float4*)O0)[idx];
    float4 b = (s < 2048) ? ((const float4*)O1lo)[idx]
                          : ((const float4*)O1hi)[idx - 2048 * 256];
    const int sh = idx >> 4;                          // = s*16 + h
    const float rinv = 1.0f / (lsums[sh] + lsums[S_LEN * NHEADS + sh]);
    bf16x4 r = { (bf16)((a.x + b.x) * rinv), (bf16)((a.y + b.y) * rinv),
                 (bf16)((a.z + b.z) * rinv), (bf16)((a.w + b.w) * rinv) };
    ((bf16x4*)ctxn)[idx] = r;
}

// ---------------------------------------------------------------------------
extern "C" void kernel_launch(void* const* d_in, const int* in_sizes, int n_in,
                              void* d_out, int out_size, void* d_ws, size_t ws_size,
                              hipStream_t stream)
{
    (void)in_sizes; (void)n_in; (void)out_size; (void)ws_size;
    const float* q  = (const float*)d_in[0];
    const float* k  = (const float*)d_in[1];
    const float* v  = (const float*)d_in[2];
    const float* Wq = (const float*)d_in[3];
    const float* bq = (const float*)d_in[4];
    const float* Wk = (const float*)d_in[5];
    const float* bk = (const float*)d_in[6];
    const float* Wv = (const float*)d_in[7];
    const float* bv = (const float*)d_in[8];
    const float* Wo = (const float*)d_in[9];
    const float* bo = (const float*)d_in[10];

    // workspace layout (bf16), 64 MiB total:
    //  [Xq 8M][Xk 8M][Xv 8M][Wqb 2M][Wkb 2M][Wvb 2M][Wob 2M][Qh 8M][Kh 8M][Vt 8M][CTX 8M]
    bf16* Xq  = (bf16*)d_ws;
    bf16* Xk  = Xq  + ACT;
    bf16* Xv  = Xk  + ACT;
    bf16* Wqb = Xv  + ACT;
    bf16* Wkb = Wqb + WELE;
    bf16* Wvb = Wkb + WELE;
    bf16* Wob = Wvb + WELE;
    bf16* Qh  = Wob + WELE;  // [h][s][dk] swizzled
    bf16* Kh  = Qh  + ACT;   // [h][t][dk] swizzled
    bf16* Vt  = Kh  + ACT;   // [h][T][dk][64] swizzled, tiled
    bf16* CTX = Vt  + ACT;   // [s][1024] (region reused as O1lo during flash)

    // f32 partial buffers for flash (all regions dead during flash):
    //  O0   (16 MiB) overlays Xq+Xk
    //  O1lo ( 8 MiB) overlays CTX   (rows 0..2047)
    //  O1hi ( 8 MiB) overlays Xv    (rows 2048..4095)
    //  lsums (512 KiB) overlays Wkb
    // combine writes bf16 ctx into Qh region (dead after flash).
    float* O0    = (float*)Xq;
    float* O1lo  = (float*)CTX;
    float* O1hi  = (float*)Xv;
    float* lsums = (float*)Wkb;
    bf16*  CTXn  = Qh;

    cvt7<<<dim3(ACT / 4 / 256, 7), 256, 0, stream>>>(
        q, k, v, Wq, Wk, Wv, Wo,
        Xq, Xk, Xv, Wqb, Wkb, Wvb, Wob, ACT / 4, WELE / 4);

    const float qscale = 0.125f * 1.4426950408889634f;  // 1/sqrt(Dk) * log2(e)
    proj_qkv<<<dim3(S_LEN / 128, DMODEL / 128, 3), 256, 0, stream>>>(
        Xq, Wqb, bq, Qh, Xk, Wkb, bk, Kh, Xv, Wvb, bv, Vt, qscale);

    flash_attn<<<dim3(S_LEN / 256, NHEADS, 2), 256, 0, stream>>>(
        Qh, Kh, Vt, O0, O1lo, O1hi, lsums);

    combine<<<dim3(ACT / 4 / 256), 256, 0, stream>>>(O0, O1lo, O1hi, lsums, CTXn);

    gemm_out<<<dim3(S_LEN / 64, DMODEL / 128), 256, 0, stream>>>(CTXn, Wob, bo, (float*)d_out);
}